// Round 13
// baseline (124.130 us; speedup 1.0000x reference)
//
#include <hip/hip_runtime.h>
#include <hip/hip_fp16.h>

// GCN 2-layer, split pipeline, atomic-free bucket pass.
//   k_bucket: 391 blocks x 4096 edges; bin by col>>9 into OWNER-EXCLUSIVE
//             subregions gbuf[blk][bucket][0..CAP) + cnt matrix (no global
//             atomics; rare >CAP spills -> tiny overflow list).
//   k_build : 196 blocks x 512 thr; bucket totals from cnt matrix (L2), scan,
//             per-node hist/place in LDS -> offs/dinv/erow; xs = fp16(dinv*x).
//   k_agg1  : gather xs (16-wide fp16) + dense chain (W1+b1,relu,W2,dinv) -> h2s
//   k_agg2  : gather h2s + bias -> out fp32
// Constants assume N=100000, E=1600000.
#define NB 196         // ceil(N/512) buckets
#define NPB 512        // nodes per bucket
#define CAP 56         // slots per (block,bucket); mean fill ~21, 7.6 sigma
#define NBLK 391       // ceil(E/4096) bucket blocks
#define OVCAP 8192     // overflow list capacity
#define REGION 10240   // per-bucket edge cap (mean 8163)
#define ECAP1 4224     // erow LDS tile, agg1; aliases hh
#define ECAP2 2560     // erow LDS tile, agg2

// ---- Pass 1: owner-exclusive binning, packed (row<<9)|(col&511) ----
__global__ __launch_bounds__(512) void k_bucket(
    const int* __restrict__ row, const int* __restrict__ col,
    unsigned* __restrict__ gbuf, int* __restrict__ cnt,
    int* __restrict__ ovf, int* __restrict__ ovfc, int E) {
    __shared__ unsigned sbuf[NB][CAP];   // 43.9 KB
    __shared__ int scnt[NB];
    const int blk = blockIdx.x, tid = threadIdx.x;
    int beg = blk * 4096;
    int end = beg + 4096; if (end > E) end = E;
    if (tid < NB) scnt[tid] = 0;
    __syncthreads();
    int base = beg + tid * 8;
    if (base < end) {
        int r[8], c[8];
        if (base + 8 <= end) {
            const int4* rp = (const int4*)(row + base);
            const int4* cp = (const int4*)(col + base);
            int4 a = rp[0], b = rp[1], d = cp[0], e = cp[1];
            r[0]=a.x; r[1]=a.y; r[2]=a.z; r[3]=a.w; r[4]=b.x; r[5]=b.y; r[6]=b.z; r[7]=b.w;
            c[0]=d.x; c[1]=d.y; c[2]=d.z; c[3]=d.w; c[4]=e.x; c[5]=e.y; c[6]=e.z; c[7]=e.w;
        } else {
            for (int j = 0; j < 8; ++j) {
                int e2 = base + j;
                r[j] = (e2 < end) ? row[e2] : -1;
                c[j] = (e2 < end) ? col[e2] : -1;
            }
        }
#pragma unroll
        for (int j = 0; j < 8; ++j) {
            if (c[j] < 0) continue;
            int b_ = c[j] >> 9;
            unsigned pk = ((unsigned)r[j] << 9) | (unsigned)(c[j] & 511);
            int p = atomicAdd(&scnt[b_], 1);          // LDS only
            if (p < CAP) sbuf[b_][p] = pk;
            else {  // ~1e-9 probability; correctness net
                int g = atomicAdd(ovfc, 1);
                if (g < OVCAP) { ovf[2*g] = b_; ovf[2*g+1] = (int)pk; }
            }
        }
    }
    __syncthreads();
    // exclusive copy-out: 2 threads per bucket + count write
    for (int t = tid; t < NB * 2; t += 512) {
        int b_ = t >> 1, half = t & 1;
        int n = scnt[b_]; if (n > CAP) n = CAP;
        unsigned* dst = gbuf + ((size_t)blk * NB + b_) * CAP;
        int lo = half ? (n >> 1) : 0;
        int hi = half ? n : (n >> 1);
        for (int i = lo; i < hi; ++i) dst[i] = sbuf[b_][i];
        if (!half) cnt[blk * NB + b_] = n;
    }
}

// ---- Pass 2: per-bucket (512 nodes) CSR in LDS; emits offs, dinv, erow, xs ----
__global__ __launch_bounds__(512) void k_build(
    const unsigned* __restrict__ gbuf, const int* __restrict__ cnt,
    const int* __restrict__ ovf, const int* __restrict__ ovfc,
    const float* __restrict__ x,
    int* __restrict__ offs, float* __restrict__ dinv,
    int* __restrict__ erow, __half* __restrict__ xs, int N, int nblk) {
    __shared__ int T[NB];
    __shared__ int sc[NPB];       // scan buffer (512)
    __shared__ int hist[NPB];
    __shared__ int pos[NPB];
    __shared__ int erow_l[REGION];  // 40 KB
    const int b = blockIdx.x, tid = threadIdx.x;
    // bucket totals from count matrix (L2-resident, 306 KB)
    if (tid < NB) {
        int sum = 0;
        for (int blk = 0; blk < nblk; ++blk) sum += cnt[blk * NB + tid];
        T[tid] = sum;
    }
    __syncthreads();
    int novf = *ovfc; if (novf > OVCAP) novf = OVCAP;
    for (int i = tid; i < novf; i += 512) atomicAdd(&T[ovf[2*i]], 1);
    __syncthreads();
    // scan T (196 <= 512)
    int tv = (tid < NB) ? T[tid] : 0;
    sc[tid] = tv;
    __syncthreads();
    for (int d = 1; d < 512; d <<= 1) {
        int t = (tid >= d) ? sc[tid - d] : 0;
        __syncthreads();
        sc[tid] += t;
        __syncthreads();
    }
    int eb = sc[b] - T[b];
    if (b == 0 && tid == 0) offs[N] = sc[NB - 1];
    int nloc = T[b]; if (nloc > REGION) nloc = REGION;
    // histogram pass over column b of the owner matrix
    hist[tid] = 0;
    __syncthreads();
    if (tid < nblk) {
        int n = cnt[tid * NB + b]; if (n > CAP) n = CAP;
        const unsigned* src = gbuf + ((size_t)tid * NB + b) * CAP;
        for (int i = 0; i < n; ++i) atomicAdd(&hist[src[i] & 511u], 1);
    }
    for (int i = tid; i < novf; i += 512)
        if (ovf[2*i] == b) atomicAdd(&hist[(unsigned)ovf[2*i+1] & 511u], 1);
    __syncthreads();
    int deg = hist[tid];
    sc[tid] = deg;
    __syncthreads();
    for (int d = 1; d < 512; d <<= 1) {
        int t = (tid >= d) ? sc[tid - d] : 0;
        __syncthreads();
        sc[tid] += t;
        __syncthreads();
    }
    int excl = sc[tid] - deg;
    pos[tid] = excl;
    float di = rsqrtf((float)deg + 1.0f);
    int gn = b * NPB + tid;
    if (gn < N) {
        offs[gn] = eb + excl;
        dinv[gn] = di;
        // xs = fp16(dinv * x)
        const float4* xp = (const float4*)(x + (size_t)gn * 16);
        float4 v0 = xp[0], v1 = xp[1], v2 = xp[2], v3 = xp[3];
        float4 st[2]; __half2* pp = (__half2*)st;
        pp[0] = __floats2half2_rn(di * v0.x, di * v0.y);
        pp[1] = __floats2half2_rn(di * v0.z, di * v0.w);
        pp[2] = __floats2half2_rn(di * v1.x, di * v1.y);
        pp[3] = __floats2half2_rn(di * v1.z, di * v1.w);
        pp[4] = __floats2half2_rn(di * v2.x, di * v2.y);
        pp[5] = __floats2half2_rn(di * v2.z, di * v2.w);
        pp[6] = __floats2half2_rn(di * v3.x, di * v3.y);
        pp[7] = __floats2half2_rn(di * v3.z, di * v3.w);
        float4* dst = (float4*)(xs + (size_t)gn * 16);
        dst[0] = st[0]; dst[1] = st[1];
    }
    __syncthreads();
    // place pass (gbuf column now L2-hot)
    if (tid < nblk) {
        int n = cnt[tid * NB + b]; if (n > CAP) n = CAP;
        const unsigned* src = gbuf + ((size_t)tid * NB + b) * CAP;
        for (int i = 0; i < n; ++i) {
            unsigned u = src[i];
            int p = atomicAdd(&pos[u & 511u], 1);
            if (p < REGION) erow_l[p] = (int)(u >> 9);
        }
    }
    for (int i = tid; i < novf; i += 512)
        if (ovf[2*i] == b) {
            unsigned u = (unsigned)ovf[2*i+1];
            int p = atomicAdd(&pos[u & 511u], 1);
            if (p < REGION) erow_l[p] = (int)(u >> 9);
        }
    __syncthreads();
    for (int i = tid; i < nloc; i += 512) erow[eb + i] = erow_l[i];
}

// accumulate 8 halfs (as float4 raw) into 8 fp32
__device__ inline void acc8(float4 v, float* s) {
    const __half2* hp = (const __half2*)&v;
#pragma unroll
    for (int k = 0; k < 4; ++k) {
        float2 f = __half22float2(hp[k]);
        s[2*k]   += f.x;
        s[2*k+1] += f.y;
    }
}

// ---- Fused: layer-1 gather-sum over xs (128 nodes/block, 2 lanes/node)
//      + dense chain (dinv, @W1+b1, relu, @W2, dinv) in LDS -> h2s (fp16) ----
__global__ void k_agg1(const int* __restrict__ offs, const int* __restrict__ erow,
                       const __half* __restrict__ xs, const float* __restrict__ dinv,
                       const float* __restrict__ W1, const float* __restrict__ b1,
                       const float* __restrict__ W2, __half* __restrict__ h2s, int N) {
    __shared__ int offL[129];
    __shared__ float w1s[512];  // 16x32 row-major [c][k]
    __shared__ float w2s[512];  // 32x16 row-major [k][j]
    __shared__ float b1s[32];
    __shared__ float hv[128][17];
    __shared__ __align__(16) char ubuf[16896]; // eL[4224] aliased with hh[128][33]
    int* eL = (int*)ubuf;
    float (*hh)[33] = (float(*)[33])ubuf;
    int tid = threadIdx.x;
    for (int t = tid; t < 512; t += 256) { w1s[t] = W1[t]; w2s[t] = W2[t]; }
    if (tid < 32) b1s[tid] = b1[tid];
    int n0 = blockIdx.x * 128;
    int nn = N - n0; if (nn > 128) nn = 128;
    for (int i = tid; i <= nn; i += 256) offL[i] = offs[n0 + i];
    __syncthreads();
    int base = offL[0];
    int cnt_ = offL[nn] - base; if (cnt_ > ECAP1) cnt_ = ECAP1;
    for (int i = tid; i < cnt_; i += 256) eL[i] = erow[base + i];
    __syncthreads();
    int m = tid >> 1;
    int q = tid & 1;
    int n = n0 + m;
    float di = 0.0f;
    if (m < nn) {
        float s[8] = {0,0,0,0,0,0,0,0};
        di = dinv[n];
        const __half* hq = xs + q * 8;
        acc8(*(const float4*)(hq + (size_t)n * 16), s);  // self loop
        int e0 = offL[m], e1 = offL[m + 1];
        int elim = base + ECAP1; if (elim > e1) elim = e1;
        int e = e0;
        for (; e + 3 < elim; e += 4) {
            int r0 = eL[e - base], r1 = eL[e + 1 - base];
            int r2 = eL[e + 2 - base], r3 = eL[e + 3 - base];
            float4 v0 = *(const float4*)(hq + (size_t)r0 * 16);
            float4 v1 = *(const float4*)(hq + (size_t)r1 * 16);
            float4 v2 = *(const float4*)(hq + (size_t)r2 * 16);
            float4 v3 = *(const float4*)(hq + (size_t)r3 * 16);
            acc8(v0, s); acc8(v1, s); acc8(v2, s); acc8(v3, s);
        }
        for (; e < elim; ++e) {
            int r = eL[e - base];
            acc8(*(const float4*)(hq + (size_t)r * 16), s);
        }
        for (; e < e1; ++e) {
            int r = erow[e];
            acc8(*(const float4*)(hq + (size_t)r * 16), s);
        }
#pragma unroll
        for (int j = 0; j < 8; ++j) hv[m][q * 8 + j] = di * s[j];
    }
    __syncthreads();  // eL dead; hh may overwrite
    if (m < nn) {
        int k0 = q * 16;
        float hid[16];
#pragma unroll
        for (int k = 0; k < 16; ++k) hid[k] = b1s[k0 + k];
#pragma unroll
        for (int c = 0; c < 16; ++c) {
            float a = hv[m][c];
#pragma unroll
            for (int k = 0; k < 16; ++k)
                hid[k] = fmaf(a, w1s[c * 32 + k0 + k], hid[k]);
        }
#pragma unroll
        for (int k = 0; k < 16; ++k) hh[m][k0 + k] = fmaxf(hid[k], 0.0f);
    }
    __syncthreads();
    if (m < nn) {
        int j0 = q * 8;
        float o[8] = {0,0,0,0,0,0,0,0};
#pragma unroll
        for (int k = 0; k < 32; ++k) {
            float a = hh[m][k];
#pragma unroll
            for (int j = 0; j < 8; ++j)
                o[j] = fmaf(a, w2s[k * 16 + j0 + j], o[j]);
        }
        float4 st;
        __half2* pp = (__half2*)&st;
#pragma unroll
        for (int p = 0; p < 4; ++p)
            pp[p] = __floats2half2_rn(di * o[2*p], di * o[2*p+1]);
        *(float4*)(h2s + (size_t)n * 16 + j0) = st;
    }
}

// ---- Layer-2 gather-sum (128 nodes/block, 2 lanes/node) + bias -> out ----
__global__ void k_agg2(const int* __restrict__ offs, const int* __restrict__ erow,
                       const __half* __restrict__ h, const float* __restrict__ dinv,
                       const float* __restrict__ b2, float* __restrict__ out, int N) {
    __shared__ int offL[129];
    __shared__ int eL[ECAP2];
    int tid = threadIdx.x;
    int n0 = blockIdx.x * 128;
    int nn = N - n0; if (nn > 128) nn = 128;
    for (int i = tid; i <= nn; i += 256) offL[i] = offs[n0 + i];
    __syncthreads();
    int base = offL[0];
    int cnt_ = offL[nn] - base; if (cnt_ > ECAP2) cnt_ = ECAP2;
    for (int i = tid; i < cnt_; i += 256) eL[i] = erow[base + i];
    __syncthreads();
    int m = tid >> 1;
    int q = tid & 1;
    int n = n0 + m;
    if (m >= nn) return;
    float s[8] = {0,0,0,0,0,0,0,0};
    const __half* hq = h + q * 8;
    acc8(*(const float4*)(hq + (size_t)n * 16), s);  // self loop
    int e0 = offL[m], e1 = offL[m + 1];
    int elim = base + ECAP2; if (elim > e1) elim = e1;
    int e = e0;
    for (; e + 3 < elim; e += 4) {
        int r0 = eL[e - base], r1 = eL[e + 1 - base];
        int r2 = eL[e + 2 - base], r3 = eL[e + 3 - base];
        float4 v0 = *(const float4*)(hq + (size_t)r0 * 16);
        float4 v1 = *(const float4*)(hq + (size_t)r1 * 16);
        float4 v2 = *(const float4*)(hq + (size_t)r2 * 16);
        float4 v3 = *(const float4*)(hq + (size_t)r3 * 16);
        acc8(v0, s); acc8(v1, s); acc8(v2, s); acc8(v3, s);
    }
    for (; e < elim; ++e) {
        int r = eL[e - base];
        acc8(*(const float4*)(hq + (size_t)r * 16), s);
    }
    for (; e < e1; ++e) {
        int r = erow[e];
        acc8(*(const float4*)(hq + (size_t)r * 16), s);
    }
    float di = dinv[n];
    float4 ba = *(const float4*)(b2 + q * 8);
    float4 bb = *(const float4*)(b2 + q * 8 + 4);
    float4* op = (float4*)(out + (size_t)n * 16 + q * 8);
    op[0] = make_float4(fmaf(di, s[0], ba.x), fmaf(di, s[1], ba.y),
                        fmaf(di, s[2], ba.z), fmaf(di, s[3], ba.w));
    op[1] = make_float4(fmaf(di, s[4], bb.x), fmaf(di, s[5], bb.y),
                        fmaf(di, s[6], bb.z), fmaf(di, s[7], bb.w));
}

extern "C" void kernel_launch(void* const* d_in, const int* in_sizes, int n_in,
                              void* d_out, int out_size, void* d_ws, size_t ws_size,
                              hipStream_t stream) {
    const float* x  = (const float*)d_in[0];
    const int*   ei = (const int*)d_in[1];
    const float* W1 = (const float*)d_in[2];
    const float* b1 = (const float*)d_in[3];
    const float* W2 = (const float*)d_in[4];
    const float* b2 = (const float*)d_in[5];
    float* out = (float*)d_out;

    const int N = in_sizes[0] / 16;
    const int E = in_sizes[1] / 2;
    const int* row = ei;
    const int* col = ei + E;
    const int nblk = (E + 4095) / 4096;            // 391

    float* ws   = (float*)d_ws;
    float* dinv = ws;                              // N floats
    __half* xs  = (__half*)(dinv + N);             // 16N halfs
    __half* h2s = xs + (size_t)N * 16;             // 16N halfs
    int* offs  = (int*)(h2s + (size_t)N * 16);     // N+1
    int* erow  = offs + N + 1;                     // E
    int* cnt   = erow + E;                         // NBLK*NB
    int* ovfc  = cnt + NBLK * NB;                  // 1
    int* ovf   = ovfc + 1;                         // 2*OVCAP
    unsigned* gbuf = (unsigned*)(ovf + 2 * OVCAP); // NBLK*NB*CAP (~17.2 MB)

    hipMemsetAsync(ovfc, 0, sizeof(int), stream);
    k_bucket<<<nblk, 512, 0, stream>>>(row, col, gbuf, cnt, ovf, ovfc, E);
    k_build<<<NB, 512, 0, stream>>>(gbuf, cnt, ovf, ovfc, x, offs, dinv, erow, xs, N, nblk);
    k_agg1<<<(N + 127) / 128, 256, 0, stream>>>(offs, erow, xs, dinv, W1, b1, W2, h2s, N);
    k_agg2<<<(N + 127) / 128, 256, 0, stream>>>(offs, erow, h2s, dinv, b2, out, N);
}

// Round 14
// 97.569 us; speedup vs baseline: 1.2722x; 1.2722x over previous
//
#include <hip/hip_runtime.h>
#include <hip/hip_fp16.h>

// GCN 2-layer, split pipeline, deterministic (atomic-free) bucket placement.
//   k_count : 391 blocks; LDS-histogram col>>9; write cntT[bucket][blk].
//   k_bucket: 391 blocks; per-bucket base = prefix of cntT row (contiguous
//             reads); LDS-stage edges; copy to exclusive dense slots. No
//             global atomics anywhere.
//   k_build : (R12-proven) per-bucket CSR in LDS -> offs/dinv/erow; xs.
//   k_agg1  : gather xs + dense chain (W1+b1,relu,W2,dinv) -> h2s (fp16)
//   k_agg2  : gather h2s + bias -> out (fp32)
// Constants assume N=100000, E=1600000.
#define NB 196         // ceil(N/512) buckets
#define NPB 512        // nodes per bucket
#define BCAP 40        // LDS staging slots per bucket (mean fill ~21)
#define NBLKP 392      // padded row length of cntT (nblk=391)
#define REGION 10240   // per-bucket region; mean fill ~8163
#define ECAP1 4224     // erow LDS tile, agg1; aliases hh
#define ECAP2 2560     // erow LDS tile, agg2

// ---- Pass 0: per-(block,bucket) counts ----
__global__ __launch_bounds__(512) void k_count(
    const int* __restrict__ col, int* __restrict__ cntT, int E) {
    __shared__ int scnt[NB];
    const int blk = blockIdx.x, tid = threadIdx.x;
    if (tid < NB) scnt[tid] = 0;
    __syncthreads();
    int beg = blk * 4096;
    int end = beg + 4096; if (end > E) end = E;
    int base = beg + tid * 8;
    if (base < end) {
        int c[8];
        if (base + 8 <= end) {
            const int4* cp = (const int4*)(col + base);
            int4 d = cp[0], e = cp[1];
            c[0]=d.x; c[1]=d.y; c[2]=d.z; c[3]=d.w; c[4]=e.x; c[5]=e.y; c[6]=e.z; c[7]=e.w;
        } else {
            for (int j = 0; j < 8; ++j) {
                int e2 = base + j;
                c[j] = (e2 < end) ? col[e2] : -1;
            }
        }
#pragma unroll
        for (int j = 0; j < 8; ++j)
            if (c[j] >= 0) atomicAdd(&scnt[c[j] >> 9], 1);
    }
    __syncthreads();
    if (tid < NB) cntT[tid * NBLKP + blk] = scnt[tid];
}

// ---- Pass 1: deterministic binning, packed (row<<9)|(col&511) ----
__global__ __launch_bounds__(512) void k_bucket(
    const int* __restrict__ row, const int* __restrict__ col,
    const int* __restrict__ cntT, unsigned* __restrict__ gbuf, int E) {
    __shared__ unsigned sbuf[NB][BCAP];   // 31.4 KB
    __shared__ int scnt[NB];
    __shared__ int basL[NB];
    const int blk = blockIdx.x, tid = threadIdx.x;
    if (tid < NB) {
        const int* cr = cntT + tid * NBLKP;
        int s = 0;
#pragma unroll 4
        for (int i = 0; i < blk; ++i) s += cr[i];
        basL[tid] = s;
        scnt[tid] = 0;
    }
    __syncthreads();
    int beg = blk * 4096;
    int end = beg + 4096; if (end > E) end = E;
    int base = beg + tid * 8;
    if (base < end) {
        int r[8], c[8];
        if (base + 8 <= end) {
            const int4* rp = (const int4*)(row + base);
            const int4* cp = (const int4*)(col + base);
            int4 a = rp[0], b = rp[1], d = cp[0], e = cp[1];
            r[0]=a.x; r[1]=a.y; r[2]=a.z; r[3]=a.w; r[4]=b.x; r[5]=b.y; r[6]=b.z; r[7]=b.w;
            c[0]=d.x; c[1]=d.y; c[2]=d.z; c[3]=d.w; c[4]=e.x; c[5]=e.y; c[6]=e.z; c[7]=e.w;
        } else {
            for (int j = 0; j < 8; ++j) {
                int e2 = base + j;
                r[j] = (e2 < end) ? row[e2] : -1;
                c[j] = (e2 < end) ? col[e2] : -1;
            }
        }
#pragma unroll
        for (int j = 0; j < 8; ++j) {
            if (c[j] < 0) continue;
            int b_ = c[j] >> 9;
            unsigned pk = ((unsigned)r[j] << 9) | (unsigned)(c[j] & 511);
            int p = atomicAdd(&scnt[b_], 1);          // LDS only
            if (p < BCAP) sbuf[b_][p] = pk;
            else {  // deterministic slot known -> direct global write
                int g = basL[b_] + p;
                if (g < REGION) gbuf[(size_t)b_ * REGION + g] = pk;
            }
        }
    }
    __syncthreads();
    // exclusive copy-out: 4 threads per bucket
    for (int t = tid; t < NB * 4; t += 512) {
        int b_ = t >> 2, part = t & 3;
        int n = scnt[b_]; if (n > BCAP) n = BCAP;
        if (n <= 0) continue;
        int g0 = basL[b_];
        int lo = (n * part) >> 2;
        int hi = (n * (part + 1)) >> 2;
        for (int i = lo; i < hi; ++i) {
            int g = g0 + i;
            if (g < REGION) gbuf[(size_t)b_ * REGION + g] = sbuf[b_][i];
        }
    }
}

// ---- Pass 2: per-bucket (512 nodes) CSR in LDS; emits offs, dinv, erow, xs ----
__global__ void k_build(const unsigned* __restrict__ gbuf, const int* __restrict__ cntT,
                        const float* __restrict__ x,
                        int* __restrict__ offs, float* __restrict__ dinv,
                        int* __restrict__ erow, __half* __restrict__ xs,
                        int N, int nblk) {
    __shared__ int s[256];
    __shared__ int Tb[256];
    __shared__ int hist[NPB];
    __shared__ int pos[NPB];
    __shared__ int psum[256];
    __shared__ int erow_l[REGION];  // 40 KB
    __shared__ int eb_s;
    int b = blockIdx.x;
    int tid = threadIdx.x;
    // bucket totals: contiguous row-sum of cntT
    int v = 0;
    if (tid < NB) {
        const int* cr = cntT + tid * NBLKP;
#pragma unroll 4
        for (int i = 0; i < nblk; ++i) v += cr[i];
        if (v > REGION) v = REGION;
    }
    Tb[tid] = v;
    s[tid] = v;
    __syncthreads();
    for (int d = 1; d < 256; d <<= 1) {
        int t = (tid >= d) ? s[tid - d] : 0;
        __syncthreads();
        s[tid] += t;
        __syncthreads();
    }
    if (tid == b) eb_s = s[tid] - v;               // exclusive base for bucket b
    if (b == 0 && tid == NB - 1) offs[N] = s[tid]; // total edge count
    __syncthreads();
    int eb = eb_s;
    int nloc = Tb[b];
    const unsigned* ebuf = gbuf + (size_t)b * REGION;
    hist[tid] = 0; hist[tid + 256] = 0;
    __syncthreads();
    for (int i = tid; i < nloc; i += 256) atomicAdd(&hist[ebuf[i] & 511u], 1);
    __syncthreads();
    int h0 = hist[2*tid], h1 = hist[2*tid+1];
    psum[tid] = h0 + h1;
    __syncthreads();
    for (int d = 1; d < 256; d <<= 1) {
        int t = (tid >= d) ? psum[tid - d] : 0;
        __syncthreads();
        psum[tid] += t;
        __syncthreads();
    }
    int basep = (tid > 0) ? psum[tid - 1] : 0;
    int e0 = basep, e1 = e0 + h0;
    pos[2*tid] = e0; pos[2*tid+1] = e1;
    int gn = b * NPB + 2 * tid;
    float di0 = rsqrtf((float)h0 + 1.0f);
    float di1 = rsqrtf((float)h1 + 1.0f);
    if (gn   < N) { offs[gn]   = eb + e0; dinv[gn]   = di0; }
    if (gn+1 < N) { offs[gn+1] = eb + e1; dinv[gn+1] = di1; }
    __syncthreads();
    for (int i = tid; i < nloc; i += 256) {
        unsigned pk = ebuf[i];
        int p = atomicAdd(&pos[pk & 511u], 1);
        erow_l[p] = (int)(pk >> 9);
    }
    __syncthreads();
    for (int i = tid; i < nloc; i += 256) erow[eb + i] = erow_l[i];
    // xs = fp16(dinv * x) for own 2 nodes
#pragma unroll
    for (int w = 0; w < 2; ++w) {
        int n = gn + w;
        if (n < N) {
            float di = w ? di1 : di0;
            const float4* xp = (const float4*)(x + (size_t)n * 16);
            float4 v0 = xp[0], v1 = xp[1], v2 = xp[2], v3 = xp[3];
            float4 st[2]; __half2* pp = (__half2*)st;
            pp[0] = __floats2half2_rn(di * v0.x, di * v0.y);
            pp[1] = __floats2half2_rn(di * v0.z, di * v0.w);
            pp[2] = __floats2half2_rn(di * v1.x, di * v1.y);
            pp[3] = __floats2half2_rn(di * v1.z, di * v1.w);
            pp[4] = __floats2half2_rn(di * v2.x, di * v2.y);
            pp[5] = __floats2half2_rn(di * v2.z, di * v2.w);
            pp[6] = __floats2half2_rn(di * v3.x, di * v3.y);
            pp[7] = __floats2half2_rn(di * v3.z, di * v3.w);
            float4* dst = (float4*)(xs + (size_t)n * 16);
            dst[0] = st[0]; dst[1] = st[1];
        }
    }
}

// accumulate 8 halfs (as float4 raw) into 8 fp32
__device__ inline void acc8(float4 v, float* s) {
    const __half2* hp = (const __half2*)&v;
#pragma unroll
    for (int k = 0; k < 4; ++k) {
        float2 f = __half22float2(hp[k]);
        s[2*k]   += f.x;
        s[2*k+1] += f.y;
    }
}

// ---- Fused: layer-1 gather-sum over xs (128 nodes/block, 2 lanes/node)
//      + dense chain (dinv, @W1+b1, relu, @W2, dinv) in LDS -> h2s (fp16) ----
__global__ void k_agg1(const int* __restrict__ offs, const int* __restrict__ erow,
                       const __half* __restrict__ xs, const float* __restrict__ dinv,
                       const float* __restrict__ W1, const float* __restrict__ b1,
                       const float* __restrict__ W2, __half* __restrict__ h2s, int N) {
    __shared__ int offL[129];
    __shared__ float w1s[512];  // 16x32 row-major [c][k]
    __shared__ float w2s[512];  // 32x16 row-major [k][j]
    __shared__ float b1s[32];
    __shared__ float hv[128][17];
    __shared__ __align__(16) char ubuf[16896]; // eL[4224] aliased with hh[128][33]
    int* eL = (int*)ubuf;
    float (*hh)[33] = (float(*)[33])ubuf;
    int tid = threadIdx.x;
    for (int t = tid; t < 512; t += 256) { w1s[t] = W1[t]; w2s[t] = W2[t]; }
    if (tid < 32) b1s[tid] = b1[tid];
    int n0 = blockIdx.x * 128;
    int nn = N - n0; if (nn > 128) nn = 128;
    for (int i = tid; i <= nn; i += 256) offL[i] = offs[n0 + i];
    __syncthreads();
    int base = offL[0];
    int cnt_ = offL[nn] - base; if (cnt_ > ECAP1) cnt_ = ECAP1;
    for (int i = tid; i < cnt_; i += 256) eL[i] = erow[base + i];
    __syncthreads();
    int m = tid >> 1;             // local node 0..127
    int q = tid & 1;              // handles halfs [q*8, q*8+8)
    int n = n0 + m;
    float di = 0.0f;
    if (m < nn) {
        float s[8] = {0,0,0,0,0,0,0,0};
        di = dinv[n];
        const __half* hq = xs + q * 8;
        acc8(*(const float4*)(hq + (size_t)n * 16), s);  // self loop
        int e0 = offL[m], e1 = offL[m + 1];
        int elim = base + ECAP1; if (elim > e1) elim = e1;
        int e = e0;
        for (; e + 3 < elim; e += 4) {  // 4-way MLP unroll
            int r0 = eL[e - base], r1 = eL[e + 1 - base];
            int r2 = eL[e + 2 - base], r3 = eL[e + 3 - base];
            float4 v0 = *(const float4*)(hq + (size_t)r0 * 16);
            float4 v1 = *(const float4*)(hq + (size_t)r1 * 16);
            float4 v2 = *(const float4*)(hq + (size_t)r2 * 16);
            float4 v3 = *(const float4*)(hq + (size_t)r3 * 16);
            acc8(v0, s); acc8(v1, s); acc8(v2, s); acc8(v3, s);
        }
        for (; e < elim; ++e) {
            int r = eL[e - base];
            acc8(*(const float4*)(hq + (size_t)r * 16), s);
        }
        for (; e < e1; ++e) {  // overflow fallback: global erow
            int r = erow[e];
            acc8(*(const float4*)(hq + (size_t)r * 16), s);
        }
#pragma unroll
        for (int j = 0; j < 8; ++j) hv[m][q * 8 + j] = di * s[j];
    }
    __syncthreads();  // eL dead beyond here; hh may overwrite it
    if (m < nn) {
        int k0 = q * 16;
        float hid[16];
#pragma unroll
        for (int k = 0; k < 16; ++k) hid[k] = b1s[k0 + k];
#pragma unroll
        for (int c = 0; c < 16; ++c) {
            float a = hv[m][c];
#pragma unroll
            for (int k = 0; k < 16; ++k)
                hid[k] = fmaf(a, w1s[c * 32 + k0 + k], hid[k]);
        }
#pragma unroll
        for (int k = 0; k < 16; ++k) hh[m][k0 + k] = fmaxf(hid[k], 0.0f);
    }
    __syncthreads();  // hh ready
    if (m < nn) {
        int j0 = q * 8;
        float o[8] = {0,0,0,0,0,0,0,0};
#pragma unroll
        for (int k = 0; k < 32; ++k) {
            float a = hh[m][k];
#pragma unroll
            for (int j = 0; j < 8; ++j)
                o[j] = fmaf(a, w2s[k * 16 + j0 + j], o[j]);
        }
        float4 st;
        __half2* pp = (__half2*)&st;
#pragma unroll
        for (int p = 0; p < 4; ++p)
            pp[p] = __floats2half2_rn(di * o[2*p], di * o[2*p+1]);
        *(float4*)(h2s + (size_t)n * 16 + j0) = st;
    }
}

// ---- Layer-2 gather-sum (128 nodes/block, 2 lanes/node) + bias -> out ----
__global__ void k_agg2(const int* __restrict__ offs, const int* __restrict__ erow,
                       const __half* __restrict__ h, const float* __restrict__ dinv,
                       const float* __restrict__ b2, float* __restrict__ out, int N) {
    __shared__ int offL[129];
    __shared__ int eL[ECAP2];
    int tid = threadIdx.x;
    int n0 = blockIdx.x * 128;
    int nn = N - n0; if (nn > 128) nn = 128;
    for (int i = tid; i <= nn; i += 256) offL[i] = offs[n0 + i];
    __syncthreads();
    int base = offL[0];
    int cnt_ = offL[nn] - base; if (cnt_ > ECAP2) cnt_ = ECAP2;
    for (int i = tid; i < cnt_; i += 256) eL[i] = erow[base + i];
    __syncthreads();
    int m = tid >> 1;
    int q = tid & 1;
    int n = n0 + m;
    if (m >= nn) return;
    float s[8] = {0,0,0,0,0,0,0,0};
    const __half* hq = h + q * 8;
    acc8(*(const float4*)(hq + (size_t)n * 16), s);  // self loop
    int e0 = offL[m], e1 = offL[m + 1];
    int elim = base + ECAP2; if (elim > e1) elim = e1;
    int e = e0;
    for (; e + 3 < elim; e += 4) {  // 4-way MLP unroll
        int r0 = eL[e - base], r1 = eL[e + 1 - base];
        int r2 = eL[e + 2 - base], r3 = eL[e + 3 - base];
        float4 v0 = *(const float4*)(hq + (size_t)r0 * 16);
        float4 v1 = *(const float4*)(hq + (size_t)r1 * 16);
        float4 v2 = *(const float4*)(hq + (size_t)r2 * 16);
        float4 v3 = *(const float4*)(hq + (size_t)r3 * 16);
        acc8(v0, s); acc8(v1, s); acc8(v2, s); acc8(v3, s);
    }
    for (; e < elim; ++e) {
        int r = eL[e - base];
        acc8(*(const float4*)(hq + (size_t)r * 16), s);
    }
    for (; e < e1; ++e) {
        int r = erow[e];
        acc8(*(const float4*)(hq + (size_t)r * 16), s);
    }
    float di = dinv[n];
    float4 ba = *(const float4*)(b2 + q * 8);
    float4 bb = *(const float4*)(b2 + q * 8 + 4);
    float4* op = (float4*)(out + (size_t)n * 16 + q * 8);
    op[0] = make_float4(fmaf(di, s[0], ba.x), fmaf(di, s[1], ba.y),
                        fmaf(di, s[2], ba.z), fmaf(di, s[3], ba.w));
    op[1] = make_float4(fmaf(di, s[4], bb.x), fmaf(di, s[5], bb.y),
                        fmaf(di, s[6], bb.z), fmaf(di, s[7], bb.w));
}

extern "C" void kernel_launch(void* const* d_in, const int* in_sizes, int n_in,
                              void* d_out, int out_size, void* d_ws, size_t ws_size,
                              hipStream_t stream) {
    const float* x  = (const float*)d_in[0];
    const int*   ei = (const int*)d_in[1];
    const float* W1 = (const float*)d_in[2];
    const float* b1 = (const float*)d_in[3];
    const float* W2 = (const float*)d_in[4];
    const float* b2 = (const float*)d_in[5];
    float* out = (float*)d_out;

    const int N = in_sizes[0] / 16;
    const int E = in_sizes[1] / 2;
    const int* row = ei;
    const int* col = ei + E;
    const int nblk = (E + 4095) / 4096;            // 391

    float* ws   = (float*)d_ws;
    float* dinv = ws;                              // N floats
    __half* xs  = (__half*)(dinv + N);             // 16N halfs
    __half* h2s = xs + (size_t)N * 16;             // 16N halfs
    int* offs  = (int*)(h2s + (size_t)N * 16);     // N+1
    int* erow  = offs + N + 1;                     // E
    int* cntT  = erow + E;                         // NB*NBLKP
    unsigned* gbuf = (unsigned*)(cntT + NB * NBLKP); // NB*REGION (~8 MB)

    k_count<<<nblk, 512, 0, stream>>>(col, cntT, E);
    k_bucket<<<nblk, 512, 0, stream>>>(row, col, cntT, gbuf, E);
    k_build<<<NB, 256, 0, stream>>>(gbuf, cntT, x, offs, dinv, erow, xs, N, nblk);
    k_agg1<<<(N + 127) / 128, 256, 0, stream>>>(offs, erow, xs, dinv, W1, b1, W2, h2s, N);
    k_agg2<<<(N + 127) / 128, 256, 0, stream>>>(offs, erow, h2s, dinv, b2, out, N);
}

// Round 15
// 80.448 us; speedup vs baseline: 1.5430x; 1.2128x over previous
//
#include <hip/hip_runtime.h>
#include <hip/hip_fp16.h>

// GCN 2-layer, split pipeline (R12 structure, tuned).
//   k_bucket: 196 blocks x 8192 edges (16/thread); bin by col>>9 into 196
//             per-bucket regions via LDS staging + one global reserve-atomic
//             per (block,bucket). Chain depth 196 (was 391).
//   k_build : 196 blocks x 512 thr (1 node/thread); per-bucket CSR in LDS ->
//             offs/dinv/erow; xs = fp16(dinv*x).
//   k_agg1  : gather xs (16-wide fp16) + dense chain (W1+b1,relu,W2,dinv) -> h2s
//   k_agg2  : gather h2s + bias -> out fp32
// Constants assume N=100000, E=1600000.
#define NB 196         // ceil(N/512) buckets
#define NPB 512        // nodes per bucket
#define BCAP 80        // LDS staging slots per bucket (mean fill ~42, +6 sigma)
#define REGION 10240   // per-bucket region; mean fill ~8163
#define ECAP1 4224     // erow LDS tile, agg1; aliases hh
#define ECAP2 2560     // erow LDS tile, agg2

// ---- Pass 1: bin edges by col>>9, packed (row<<9)|(col&511) ----
__global__ __launch_bounds__(512) void k_bucket(
    const int* __restrict__ row, const int* __restrict__ col,
    unsigned* __restrict__ gbuf, int* __restrict__ gtail, int E) {
    __shared__ unsigned sbuf[NB][BCAP];   // 62.7 KB
    __shared__ int scnt[NB];
    __shared__ int gbase[NB];
    const int tid = threadIdx.x;
    int beg = blockIdx.x * 8192;
    int end = beg + 8192; if (end > E) end = E;
    if (tid < NB) scnt[tid] = 0;
    __syncthreads();
    int base = beg + tid * 16;
    if (base < end) {
        int r[16], c[16];
        if (base + 16 <= end) {
            const int4* rp = (const int4*)(row + base);
            const int4* cp = (const int4*)(col + base);
#pragma unroll
            for (int v = 0; v < 4; ++v) {
                int4 a = rp[v], d = cp[v];
                r[4*v+0]=a.x; r[4*v+1]=a.y; r[4*v+2]=a.z; r[4*v+3]=a.w;
                c[4*v+0]=d.x; c[4*v+1]=d.y; c[4*v+2]=d.z; c[4*v+3]=d.w;
            }
        } else {
            for (int j = 0; j < 16; ++j) {
                int e2 = base + j;
                r[j] = (e2 < end) ? row[e2] : -1;
                c[j] = (e2 < end) ? col[e2] : -1;
            }
        }
#pragma unroll
        for (int j = 0; j < 16; ++j) {
            if (c[j] < 0) continue;
            int b_ = c[j] >> 9;
            unsigned pk = ((unsigned)r[j] << 9) | (unsigned)(c[j] & 511);
            int p = atomicAdd(&scnt[b_], 1);          // LDS only
            if (p < BCAP) sbuf[b_][p] = pk;
            else {  // rare overflow: direct global append
                int g = atomicAdd(&gtail[b_], 1);
                if (g < REGION) gbuf[(size_t)b_ * REGION + g] = pk;
            }
        }
    }
    __syncthreads();
    if (tid < NB) {
        int n = scnt[tid]; if (n > BCAP) n = BCAP;
        gbase[tid] = (n > 0) ? atomicAdd(&gtail[tid], n) : 0;
    }
    __syncthreads();
    // copy: 4 threads per bucket, contiguous quarters
    for (int t = tid; t < NB * 4; t += 512) {
        int b_ = t >> 2, part = t & 3;
        int n = scnt[b_]; if (n > BCAP) n = BCAP;
        if (n <= 0) continue;
        int g0 = gbase[b_];
        int lo = (n * part) >> 2;
        int hi = (n * (part + 1)) >> 2;
        for (int i = lo; i < hi; ++i) {
            int g = g0 + i;
            if (g < REGION) gbuf[(size_t)b_ * REGION + g] = sbuf[b_][i];
        }
    }
}

// ---- Pass 2: per-bucket (512 nodes) CSR in LDS; emits offs, dinv, erow, xs ----
__global__ __launch_bounds__(512) void k_build(
    const unsigned* __restrict__ gbuf, const int* __restrict__ gtail,
    const float* __restrict__ x,
    int* __restrict__ offs, float* __restrict__ dinv,
    int* __restrict__ erow, __half* __restrict__ xs, int N) {
    __shared__ int sc[NPB];
    __shared__ int hist[NPB];
    __shared__ int pos[NPB];
    __shared__ int erow_l[REGION];  // 40 KB
    __shared__ int eb_s;
    const int b = blockIdx.x, tid = threadIdx.x;
    // scan clipped bucket sizes to get this bucket's base (NB=196 <= 512)
    int v = 0;
    if (tid < NB) { v = gtail[tid]; if (v > REGION) v = REGION; }
    sc[tid] = v;
    __syncthreads();
    for (int d = 1; d < NPB; d <<= 1) {
        int t = (tid >= d) ? sc[tid - d] : 0;
        __syncthreads();
        sc[tid] += t;
        __syncthreads();
    }
    if (tid == b) eb_s = sc[tid] - v;              // exclusive base for bucket b
    if (b == 0 && tid == NB - 1) offs[N] = sc[tid];
    __syncthreads();
    int eb = eb_s;
    int nloc = gtail[b]; if (nloc > REGION) nloc = REGION;
    const unsigned* ebuf = gbuf + (size_t)b * REGION;
    hist[tid] = 0;
    __syncthreads();
    for (int i = tid; i < nloc; i += 512) atomicAdd(&hist[ebuf[i] & 511u], 1);
    __syncthreads();
    int deg = hist[tid];
    sc[tid] = deg;
    __syncthreads();
    for (int d = 1; d < NPB; d <<= 1) {
        int t = (tid >= d) ? sc[tid - d] : 0;
        __syncthreads();
        sc[tid] += t;
        __syncthreads();
    }
    int excl = sc[tid] - deg;
    pos[tid] = excl;
    float di = rsqrtf((float)deg + 1.0f);
    int gn = b * NPB + tid;
    if (gn < N) { offs[gn] = eb + excl; dinv[gn] = di; }
    __syncthreads();
    for (int i = tid; i < nloc; i += 512) {
        unsigned pk = ebuf[i];
        int p = atomicAdd(&pos[pk & 511u], 1);
        erow_l[p] = (int)(pk >> 9);
    }
    __syncthreads();
    for (int i = tid; i < nloc; i += 512) erow[eb + i] = erow_l[i];
    // xs = fp16(dinv * x) for own node
    if (gn < N) {
        const float4* xp = (const float4*)(x + (size_t)gn * 16);
        float4 v0 = xp[0], v1 = xp[1], v2 = xp[2], v3 = xp[3];
        float4 st[2]; __half2* pp = (__half2*)st;
        pp[0] = __floats2half2_rn(di * v0.x, di * v0.y);
        pp[1] = __floats2half2_rn(di * v0.z, di * v0.w);
        pp[2] = __floats2half2_rn(di * v1.x, di * v1.y);
        pp[3] = __floats2half2_rn(di * v1.z, di * v1.w);
        pp[4] = __floats2half2_rn(di * v2.x, di * v2.y);
        pp[5] = __floats2half2_rn(di * v2.z, di * v2.w);
        pp[6] = __floats2half2_rn(di * v3.x, di * v3.y);
        pp[7] = __floats2half2_rn(di * v3.z, di * v3.w);
        float4* dst = (float4*)(xs + (size_t)gn * 16);
        dst[0] = st[0]; dst[1] = st[1];
    }
}

// accumulate 8 halfs (as float4 raw) into 8 fp32
__device__ inline void acc8(float4 v, float* s) {
    const __half2* hp = (const __half2*)&v;
#pragma unroll
    for (int k = 0; k < 4; ++k) {
        float2 f = __half22float2(hp[k]);
        s[2*k]   += f.x;
        s[2*k+1] += f.y;
    }
}

// ---- Fused: layer-1 gather-sum over xs (128 nodes/block, 2 lanes/node)
//      + dense chain (dinv, @W1+b1, relu, @W2, dinv) in LDS -> h2s (fp16) ----
__global__ void k_agg1(const int* __restrict__ offs, const int* __restrict__ erow,
                       const __half* __restrict__ xs, const float* __restrict__ dinv,
                       const float* __restrict__ W1, const float* __restrict__ b1,
                       const float* __restrict__ W2, __half* __restrict__ h2s, int N) {
    __shared__ int offL[129];
    __shared__ float w1s[512];  // 16x32 row-major [c][k]
    __shared__ float w2s[512];  // 32x16 row-major [k][j]
    __shared__ float b1s[32];
    __shared__ float hv[128][17];
    __shared__ __align__(16) char ubuf[16896]; // eL[4224] aliased with hh[128][33]
    int* eL = (int*)ubuf;
    float (*hh)[33] = (float(*)[33])ubuf;
    int tid = threadIdx.x;
    for (int t = tid; t < 512; t += 256) { w1s[t] = W1[t]; w2s[t] = W2[t]; }
    if (tid < 32) b1s[tid] = b1[tid];
    int n0 = blockIdx.x * 128;
    int nn = N - n0; if (nn > 128) nn = 128;
    for (int i = tid; i <= nn; i += 256) offL[i] = offs[n0 + i];
    __syncthreads();
    int base = offL[0];
    int cnt_ = offL[nn] - base; if (cnt_ > ECAP1) cnt_ = ECAP1;
    for (int i = tid; i < cnt_; i += 256) eL[i] = erow[base + i];
    __syncthreads();
    int m = tid >> 1;             // local node 0..127
    int q = tid & 1;              // handles halfs [q*8, q*8+8)
    int n = n0 + m;
    float di = 0.0f;
    if (m < nn) {
        float s[8] = {0,0,0,0,0,0,0,0};
        di = dinv[n];
        const __half* hq = xs + q * 8;
        acc8(*(const float4*)(hq + (size_t)n * 16), s);  // self loop
        int e0 = offL[m], e1 = offL[m + 1];
        int elim = base + ECAP1; if (elim > e1) elim = e1;
        int e = e0;
        for (; e + 3 < elim; e += 4) {  // 4-way MLP unroll
            int r0 = eL[e - base], r1 = eL[e + 1 - base];
            int r2 = eL[e + 2 - base], r3 = eL[e + 3 - base];
            float4 v0 = *(const float4*)(hq + (size_t)r0 * 16);
            float4 v1 = *(const float4*)(hq + (size_t)r1 * 16);
            float4 v2 = *(const float4*)(hq + (size_t)r2 * 16);
            float4 v3 = *(const float4*)(hq + (size_t)r3 * 16);
            acc8(v0, s); acc8(v1, s); acc8(v2, s); acc8(v3, s);
        }
        for (; e < elim; ++e) {
            int r = eL[e - base];
            acc8(*(const float4*)(hq + (size_t)r * 16), s);
        }
        for (; e < e1; ++e) {  // overflow fallback: global erow
            int r = erow[e];
            acc8(*(const float4*)(hq + (size_t)r * 16), s);
        }
#pragma unroll
        for (int j = 0; j < 8; ++j) hv[m][q * 8 + j] = di * s[j];
    }
    __syncthreads();  // eL dead beyond here; hh may overwrite it
    if (m < nn) {
        int k0 = q * 16;
        float hid[16];
#pragma unroll
        for (int k = 0; k < 16; ++k) hid[k] = b1s[k0 + k];
#pragma unroll
        for (int c = 0; c < 16; ++c) {
            float a = hv[m][c];
#pragma unroll
            for (int k = 0; k < 16; ++k)
                hid[k] = fmaf(a, w1s[c * 32 + k0 + k], hid[k]);
        }
#pragma unroll
        for (int k = 0; k < 16; ++k) hh[m][k0 + k] = fmaxf(hid[k], 0.0f);
    }
    __syncthreads();  // hh ready
    if (m < nn) {
        int j0 = q * 8;
        float o[8] = {0,0,0,0,0,0,0,0};
#pragma unroll
        for (int k = 0; k < 32; ++k) {
            float a = hh[m][k];
#pragma unroll
            for (int j = 0; j < 8; ++j)
                o[j] = fmaf(a, w2s[k * 16 + j0 + j], o[j]);
        }
        float4 st;
        __half2* pp = (__half2*)&st;
#pragma unroll
        for (int p = 0; p < 4; ++p)
            pp[p] = __floats2half2_rn(di * o[2*p], di * o[2*p+1]);
        *(float4*)(h2s + (size_t)n * 16 + j0) = st;
    }
}

// ---- Layer-2 gather-sum (128 nodes/block, 2 lanes/node) + bias -> out ----
__global__ void k_agg2(const int* __restrict__ offs, const int* __restrict__ erow,
                       const __half* __restrict__ h, const float* __restrict__ dinv,
                       const float* __restrict__ b2, float* __restrict__ out, int N) {
    __shared__ int offL[129];
    __shared__ int eL[ECAP2];
    int tid = threadIdx.x;
    int n0 = blockIdx.x * 128;
    int nn = N - n0; if (nn > 128) nn = 128;
    for (int i = tid; i <= nn; i += 256) offL[i] = offs[n0 + i];
    __syncthreads();
    int base = offL[0];
    int cnt_ = offL[nn] - base; if (cnt_ > ECAP2) cnt_ = ECAP2;
    for (int i = tid; i < cnt_; i += 256) eL[i] = erow[base + i];
    __syncthreads();
    int m = tid >> 1;
    int q = tid & 1;
    int n = n0 + m;
    if (m >= nn) return;
    float s[8] = {0,0,0,0,0,0,0,0};
    const __half* hq = h + q * 8;
    acc8(*(const float4*)(hq + (size_t)n * 16), s);  // self loop
    int e0 = offL[m], e1 = offL[m + 1];
    int elim = base + ECAP2; if (elim > e1) elim = e1;
    int e = e0;
    for (; e + 3 < elim; e += 4) {  // 4-way MLP unroll
        int r0 = eL[e - base], r1 = eL[e + 1 - base];
        int r2 = eL[e + 2 - base], r3 = eL[e + 3 - base];
        float4 v0 = *(const float4*)(hq + (size_t)r0 * 16);
        float4 v1 = *(const float4*)(hq + (size_t)r1 * 16);
        float4 v2 = *(const float4*)(hq + (size_t)r2 * 16);
        float4 v3 = *(const float4*)(hq + (size_t)r3 * 16);
        acc8(v0, s); acc8(v1, s); acc8(v2, s); acc8(v3, s);
    }
    for (; e < elim; ++e) {
        int r = eL[e - base];
        acc8(*(const float4*)(hq + (size_t)r * 16), s);
    }
    for (; e < e1; ++e) {
        int r = erow[e];
        acc8(*(const float4*)(hq + (size_t)r * 16), s);
    }
    float di = dinv[n];
    float4 ba = *(const float4*)(b2 + q * 8);
    float4 bb = *(const float4*)(b2 + q * 8 + 4);
    float4* op = (float4*)(out + (size_t)n * 16 + q * 8);
    op[0] = make_float4(fmaf(di, s[0], ba.x), fmaf(di, s[1], ba.y),
                        fmaf(di, s[2], ba.z), fmaf(di, s[3], ba.w));
    op[1] = make_float4(fmaf(di, s[4], bb.x), fmaf(di, s[5], bb.y),
                        fmaf(di, s[6], bb.z), fmaf(di, s[7], bb.w));
}

extern "C" void kernel_launch(void* const* d_in, const int* in_sizes, int n_in,
                              void* d_out, int out_size, void* d_ws, size_t ws_size,
                              hipStream_t stream) {
    const float* x  = (const float*)d_in[0];
    const int*   ei = (const int*)d_in[1];
    const float* W1 = (const float*)d_in[2];
    const float* b1 = (const float*)d_in[3];
    const float* W2 = (const float*)d_in[4];
    const float* b2 = (const float*)d_in[5];
    float* out = (float*)d_out;

    const int N = in_sizes[0] / 16;
    const int E = in_sizes[1] / 2;
    const int* row = ei;
    const int* col = ei + E;

    float* ws   = (float*)d_ws;
    float* dinv = ws;                              // N floats
    __half* xs  = (__half*)(dinv + N);             // 16N halfs
    __half* h2s = xs + (size_t)N * 16;             // 16N halfs
    int* offs  = (int*)(h2s + (size_t)N * 16);     // N+1
    int* erow  = offs + N + 1;                     // E
    int* gtail = erow + E;                         // NB
    unsigned* gbuf = (unsigned*)(gtail + NB);      // NB*REGION (~8 MB)

    const int nbB = (E + 8191) / 8192;             // 196

    hipMemsetAsync(gtail, 0, NB * sizeof(int), stream);
    k_bucket<<<nbB, 512, 0, stream>>>(row, col, gbuf, gtail, E);
    k_build<<<NB, 512, 0, stream>>>(gbuf, gtail, x, offs, dinv, erow, xs, N);
    k_agg1<<<(N + 127) / 128, 256, 0, stream>>>(offs, erow, xs, dinv, W1, b1, W2, h2s, N);
    k_agg2<<<(N + 127) / 128, 256, 0, stream>>>(offs, erow, h2s, dinv, b2, out, N);
}